// Round 1
// baseline (642.047 us; speedup 1.0000x reference)
//
#include <hip/hip_runtime.h>
#include <type_traits>

#define NCH   512
#define ND    16
#define NH    64
#define NW    64
#define HT    8                 // output rows per block
#define ROWS  (HT + 6)          // 14 staged rows (3-halo each side)
#define RST   72                // LDS row stride in floats (16B-aligned rows)
#define WCOLS 70                // valid staged cols (64 + 3 halo each side)
#define PLANE (NH * NW)         // 4096
#define CHVOL (ND * PLANE)      // 65536
#define WEFF_PER_CH 448         // [kh=7][kd=7][8-padded kw]

// ---------------------------------------------------------------------------
// Prologue: fold w7 + centered(w5) + centered(w3) + identity into one 7^3
// kernel per channel, transposed to [kh][kd][kw(pad8)] for SGPR-friendly
// per-kh row loads. b_eff = b7 + b5 + b3.
// ---------------------------------------------------------------------------
__global__ void build_weights(const float* __restrict__ w7,
                              const float* __restrict__ b7,
                              const float* __restrict__ w5,
                              const float* __restrict__ b5,
                              const float* __restrict__ w3,
                              const float* __restrict__ b3,
                              float* __restrict__ weff,
                              float* __restrict__ beff)
{
    const int ch = blockIdx.x;
    for (int i = threadIdx.x; i < WEFF_PER_CH; i += blockDim.x) {
        const int kh = i / 56;
        const int r  = i - kh * 56;
        const int kd = r >> 3;
        const int kw = r & 7;
        float v = 0.0f;
        if (kw < 7) {
            v = w7[ch * 343 + kd * 49 + kh * 7 + kw];
            if (kd >= 1 && kd <= 5 && kh >= 1 && kh <= 5 && kw >= 1 && kw <= 5)
                v += w5[ch * 125 + (kd - 1) * 25 + (kh - 1) * 5 + (kw - 1)];
            if (kd >= 2 && kd <= 4 && kh >= 2 && kh <= 4 && kw >= 2 && kw <= 4)
                v += w3[ch * 27 + (kd - 2) * 9 + (kh - 2) * 3 + (kw - 2)];
            if (kd == 3 && kh == 3 && kw == 3) v += 1.0f;   // identity (residual)
        }
        weff[ch * WEFF_PER_CH + kh * 56 + kd * 8 + kw] = v;
    }
    if (threadIdx.x == 0) beff[ch] = b7[ch] + b5[ch] + b3[ch];
}

// ---------------------------------------------------------------------------
// Main: one block per (channel, 8-row h tile). Stage 16 x 14 x 72 fp32 slab
// in LDS (63 KB, 2 blocks/CU). Thread = (w-strip of 4, 1 h row, 8-deep d
// half); scatter over input planes di so each LDS window is read once and
// fans out to <=7 d outputs x 7 kw x 4 w FMAs. d-half is wave-uniform.
// ---------------------------------------------------------------------------
__global__ __launch_bounds__(256, 2)
void dwconv_fused(const float* __restrict__ in,
                  const float* __restrict__ weff,
                  const float* __restrict__ beff,
                  float* __restrict__ out)
{
    __shared__ float lds[ND * ROWS * RST];   // 16128 floats = 63 KB

    const int blk = blockIdx.x;
    const int ch  = blk >> 3;
    const int ht  = blk & 7;
    const int h0  = ht * HT;
    const int tid = threadIdx.x;

    const float* __restrict__ inb = in + ch * CHVOL;

    // ---- stage input slab (zero-padded halo) -----------------------------
    for (int idx = tid; idx < ND * ROWS * WCOLS; idx += 256) {
        const int di = idx / (ROWS * WCOLS);
        const int rm = idx - di * (ROWS * WCOLS);
        const int r  = rm / WCOLS;
        const int c  = rm - r * WCOLS;
        const int ih = h0 - 3 + r;
        const int iw = c - 3;
        float v = 0.0f;
        if ((unsigned)ih < (unsigned)NH && (unsigned)iw < (unsigned)NW)
            v = inb[di * PLANE + ih * NW + iw];
        lds[(di * ROWS + r) * RST + c] = v;
    }
    __syncthreads();

    const int wg = tid & 15;          // 16 w-groups of 4
    const int hg = (tid >> 4) & 7;    // 8 h rows
    const int dg = tid >> 7;          // d half: waves 0-1 -> 0, waves 2-3 -> 1
    const int w0 = wg * 4;

    const float bv = beff[ch];
    float acc[8][4];
    #pragma unroll
    for (int a = 0; a < 8; ++a)
        #pragma unroll
        for (int j = 0; j < 4; ++j) acc[a][j] = bv;

    const float* __restrict__ wch = weff + ch * WEFF_PER_CH;

    auto run = [&](auto dbt) {
        constexpr int DB = decltype(dbt)::value;
        #pragma unroll 1
        for (int kh = 0; kh < 7; ++kh) {
            // 56 block-uniform weights for this kh -> SGPRs via SMEM
            float wreg[56];
            const float* __restrict__ wp = wch + kh * 56;
            #pragma unroll
            for (int i = 0; i < 56; ++i) wreg[i] = wp[i];

            const int row = hg + kh;  // LDS row for output row hg, tap kh
            #pragma unroll
            for (int di = 0; di < ND; ++di) {
                if (di < DB - 3 || di > DB + 10) continue;  // folds at compile time
                const float* p = &lds[(di * ROWS + row) * RST + w0];
                const float4 f0 = *(const float4*)(p);
                const float4 f1 = *(const float4*)(p + 4);
                const float2 f2 = *(const float2*)(p + 8);
                const float win[10] = {f0.x, f0.y, f0.z, f0.w,
                                       f1.x, f1.y, f1.z, f1.w,
                                       f2.x, f2.y};
                #pragma unroll
                for (int a = 0; a < 8; ++a) {
                    const int dout = DB + a;
                    const int kd   = di - dout + 3;     // input di = dout + kd - 3
                    if (kd < 0 || kd > 6) continue;     // folds at compile time
                    #pragma unroll
                    for (int kw = 0; kw < 7; ++kw) {
                        const float wt = wreg[kd * 8 + kw];
                        #pragma unroll
                        for (int j = 0; j < 4; ++j)
                            acc[a][j] = fmaf(win[kw + j], wt, acc[a][j]);
                    }
                }
            }
        }
    };
    if (dg == 0) run(std::integral_constant<int, 0>{});
    else         run(std::integral_constant<int, 8>{});

    // ---- write: out[ch][n=h*64+w][d], contiguous in d --------------------
    const int DB = dg * 8;
    const int h  = h0 + hg;
    float* __restrict__ ob = out + ch * CHVOL + (h * NW + w0) * ND + DB;
    #pragma unroll
    for (int j = 0; j < 4; ++j) {
        const float4 v0 = make_float4(acc[0][j], acc[1][j], acc[2][j], acc[3][j]);
        const float4 v1 = make_float4(acc[4][j], acc[5][j], acc[6][j], acc[7][j]);
        *(float4*)(ob + j * ND)     = v0;
        *(float4*)(ob + j * ND + 4) = v1;
    }
}

extern "C" void kernel_launch(void* const* d_in, const int* in_sizes, int n_in,
                              void* d_out, int out_size, void* d_ws, size_t ws_size,
                              hipStream_t stream)
{
    const float* x  = (const float*)d_in[0];
    const float* w7 = (const float*)d_in[1];
    const float* b7 = (const float*)d_in[2];
    const float* w5 = (const float*)d_in[3];
    const float* b5 = (const float*)d_in[4];
    const float* w3 = (const float*)d_in[5];
    const float* b3 = (const float*)d_in[6];
    float* outp = (float*)d_out;

    float* weff = (float*)d_ws;                    // 512*448 floats
    float* beff = weff + NCH * WEFF_PER_CH;        // +512 floats (~0.92 MB total)

    build_weights<<<NCH, 64, 0, stream>>>(w7, b7, w5, b5, w3, b3, weff, beff);
    dwconv_fused<<<NCH * 8, 256, 0, stream>>>(x, weff, beff, outp);
}

// Round 2
// 549.285 us; speedup vs baseline: 1.1689x; 1.1689x over previous
//
#include <hip/hip_runtime.h>
#include <type_traits>

typedef _Float16 f16;
typedef _Float16 f16x2 __attribute__((ext_vector_type(2)));
typedef unsigned int u32;
typedef unsigned short u16;

#define NCH   512
#define ND    16
#define NH    64
#define NW    64
#define HT    8                  // output rows per block
#define ROWS  (HT + 6)           // 14 staged rows
#define RSTH  72                 // halves per LDS row (exactly the 72 cols needed)
#define PLANE (NH * NW)          // 4096
#define CHVOL (ND * PLANE)       // 65536
#define WH_PER_CH 392            // halves: [kh=7][kd=7][kw pad to 8]
#define WU_PER_CH 196            // same, viewed as uint32 pairs
#define WU_PER_KH 28

#if defined(__has_builtin)
#  if __has_builtin(__builtin_amdgcn_fdot2)
#    define HAVE_FDOT2 1
#  endif
#endif
#ifndef HAVE_FDOT2
#  define HAVE_FDOT2 0
#endif

// v_dot2_f32_f16: c += a.x*b.x + a.y*b.y (fp32 accumulate, full-rate on CDNA)
__device__ __forceinline__ float fdot2u(u32 a, u32 b, float c) {
#if HAVE_FDOT2
    return __builtin_amdgcn_fdot2(__builtin_bit_cast(f16x2, a),
                                  __builtin_bit_cast(f16x2, b), c, false);
#else
    f16x2 av = __builtin_bit_cast(f16x2, a);
    f16x2 bv = __builtin_bit_cast(f16x2, b);
    return fmaf((float)av.y, (float)bv.y, fmaf((float)av.x, (float)bv.x, c));
#endif
}

__device__ __forceinline__ u16 f16bits(float v) {
    return __builtin_bit_cast(u16, (f16)v);
}

// ---------------------------------------------------------------------------
// Prologue: fold w7 + centered(w5) + centered(w3) + identity into a single
// effective 7^3 kernel per channel, stored as f16 in [kh][kd][kw(pad8=0)]
// order so each (kd) row is 4 aligned half2 pairs. b_eff = b7+b5+b3 (fp32).
// ---------------------------------------------------------------------------
__global__ void build_weights(const float* __restrict__ w7,
                              const float* __restrict__ b7,
                              const float* __restrict__ w5,
                              const float* __restrict__ b5,
                              const float* __restrict__ w3,
                              const float* __restrict__ b3,
                              u16* __restrict__ weffh,
                              float* __restrict__ beff)
{
    const int ch = blockIdx.x;
    for (int i = threadIdx.x; i < WH_PER_CH; i += blockDim.x) {
        const int kh = i / 56;
        const int r  = i - kh * 56;
        const int kd = r >> 3;
        const int kw = r & 7;
        float v = 0.0f;
        if (kw < 7) {
            v = w7[ch * 343 + kd * 49 + kh * 7 + kw];
            if (kd >= 1 && kd <= 5 && kh >= 1 && kh <= 5 && kw >= 1 && kw <= 5)
                v += w5[ch * 125 + (kd - 1) * 25 + (kh - 1) * 5 + (kw - 1)];
            if (kd >= 2 && kd <= 4 && kh >= 2 && kh <= 4 && kw >= 2 && kw <= 4)
                v += w3[ch * 27 + (kd - 2) * 9 + (kh - 2) * 3 + (kw - 2)];
            if (kd == 3 && kh == 3 && kw == 3) v += 1.0f;  // identity/residual
        }
        weffh[ch * WH_PER_CH + kh * 56 + kd * 8 + kw] = f16bits(v);
    }
    if (threadIdx.x == 0) beff[ch] = b7[ch] + b5[ch] + b3[ch];
}

// ---------------------------------------------------------------------------
// Main: block = (channel, 8-row h-tile). LDS slab staged as f16:
// 16 planes x 14 rows x 72 halves = 31.5 KB -> 4-5 blocks/CU (vs 2 at fp32).
// Thread = (4-w strip, 1 h row, 8-deep d-half); per input plane di the 12-half
// window is read once (3x ds_read_b64) and fans out to <=7 d-outputs via
// v_dot2_f32_f16 with SGPR-resident weights. d-half is wave-uniform.
// ---------------------------------------------------------------------------
__global__ __launch_bounds__(256, 4)
void dwconv_fused(const float* __restrict__ in,
                  const u32* __restrict__ weff_u,
                  const float* __restrict__ beff,
                  float* __restrict__ out)
{
    __shared__ u16 lds[ND * ROWS * RSTH];   // 32,256 B

    const int blk = blockIdx.x;
    const int ch  = blk >> 3;
    const int ht  = blk & 7;
    const int h0  = ht * HT;
    const int tid = threadIdx.x;

    const float* __restrict__ inb = in + ch * CHVOL;

    // ---- stage slab, division-free, wave-uniform row guard ---------------
    {
        const int cl = tid & 63;     // column lane (cols 0..63, +8 tail cols)
        const int rw = tid >> 6;     // wave index 0..3 -> row phase
        for (int di = 0; di < ND; ++di) {
            #pragma unroll
            for (int rr = 0; rr < 4; ++rr) {
                const int r = rw + rr * 4;          // wave-uniform
                if (r >= ROWS) continue;
                const int ih = h0 - 3 + r;
                const bool hv = (unsigned)ih < (unsigned)NH;
                const int rowbase = (di * ROWS + r) * RSTH;
                float v0 = 0.0f;
                if (hv && (unsigned)(cl - 3) < (unsigned)NW)
                    v0 = inb[di * PLANE + ih * NW + (cl - 3)];
                lds[rowbase + cl] = f16bits(v0);
                if (cl < 8) {                        // cols 64..71
                    float v1 = 0.0f;
                    if (hv && cl < 3)
                        v1 = inb[di * PLANE + ih * NW + (cl + 61)];
                    lds[rowbase + 64 + cl] = f16bits(v1);
                }
            }
        }
    }
    __syncthreads();

    const int wg = tid & 15;          // 16 w-groups of 4
    const int hg = (tid >> 4) & 7;    // 8 h rows
    const int dg = tid >> 7;          // d-half (wave-uniform)
    const int w0 = wg * 4;

    const float bv = beff[ch];
    float acc[8][4];
    #pragma unroll
    for (int a = 0; a < 8; ++a)
        #pragma unroll
        for (int j = 0; j < 4; ++j) acc[a][j] = bv;

    const u32* __restrict__ wch = weff_u + ch * WU_PER_CH;

    auto run = [&](auto dbt) {
        constexpr int DB = decltype(dbt)::value;
        #pragma unroll 1
        for (int kh = 0; kh < 7; ++kh) {
            // 28 block-uniform weight dwords for this kh -> SGPRs
            u32 wu[WU_PER_KH];
            const u32* __restrict__ wp = wch + kh * WU_PER_KH;
            #pragma unroll
            for (int i = 0; i < WU_PER_KH; ++i) wu[i] = wp[i];

            const int row = hg + kh;
            #pragma unroll
            for (int di = 0; di < ND; ++di) {
                if (di < DB - 3 || di > DB + 10) continue;   // folds
                const u16* p = &lds[(di * ROWS + row) * RSTH + w0];
                const uint2 la = *(const uint2*)(p);         // halves 0..3
                const uint2 lb = *(const uint2*)(p + 4);     // halves 4..7
                const uint2 lc = *(const uint2*)(p + 8);     // halves 8..11
                const u32 u0 = la.x, u1 = la.y, u2 = lb.x, u3 = lb.y,
                          u4 = lc.x, u5 = lc.y;
                // shifted pairs (v_alignbit): halves (2i+1, 2i+2)
                const u32 s0 = (u0 >> 16) | (u1 << 16);
                const u32 s1 = (u1 >> 16) | (u2 << 16);
                const u32 s2 = (u2 >> 16) | (u3 << 16);
                const u32 s3 = (u3 >> 16) | (u4 << 16);
                const u32 s4 = (u4 >> 16) | (u5 << 16);
                #pragma unroll
                for (int a = 0; a < 8; ++a) {
                    const int dout = DB + a;
                    const int kd   = di - dout + 3;          // folds
                    if (kd < 0 || kd > 6) continue;
                    const u32 wa = wu[kd * 4 + 0];
                    const u32 wb = wu[kd * 4 + 1];
                    const u32 wc = wu[kd * 4 + 2];
                    const u32 wd = wu[kd * 4 + 3];           // (w6, 0)
                    float a0 = acc[a][0], a1 = acc[a][1],
                          a2 = acc[a][2], a3 = acc[a][3];
                    a0 = fdot2u(u0, wa, a0); a1 = fdot2u(s0, wa, a1);
                    a2 = fdot2u(u1, wa, a2); a3 = fdot2u(s1, wa, a3);
                    a0 = fdot2u(u1, wb, a0); a1 = fdot2u(s1, wb, a1);
                    a2 = fdot2u(u2, wb, a2); a3 = fdot2u(s2, wb, a3);
                    a0 = fdot2u(u2, wc, a0); a1 = fdot2u(s2, wc, a1);
                    a2 = fdot2u(u3, wc, a2); a3 = fdot2u(s3, wc, a3);
                    a0 = fdot2u(u3, wd, a0); a1 = fdot2u(s3, wd, a1);
                    a2 = fdot2u(u4, wd, a2); a3 = fdot2u(s4, wd, a3);
                    acc[a][0] = a0; acc[a][1] = a1;
                    acc[a][2] = a2; acc[a][3] = a3;
                }
            }
        }
    };
    if (dg == 0) run(std::integral_constant<int, 0>{});
    else         run(std::integral_constant<int, 8>{});

    // ---- write out[ch][h*64+w][d], d-contiguous float4s ------------------
    const int DB = dg * 8;
    const int h  = h0 + hg;
    float* __restrict__ ob = out + ch * CHVOL + (h * NW + w0) * ND + DB;
    #pragma unroll
    for (int j = 0; j < 4; ++j) {
        const float4 v0 = make_float4(acc[0][j], acc[1][j], acc[2][j], acc[3][j]);
        const float4 v1 = make_float4(acc[4][j], acc[5][j], acc[6][j], acc[7][j]);
        *(float4*)(ob + j * ND)     = v0;
        *(float4*)(ob + j * ND + 4) = v1;
    }
}

extern "C" void kernel_launch(void* const* d_in, const int* in_sizes, int n_in,
                              void* d_out, int out_size, void* d_ws, size_t ws_size,
                              hipStream_t stream)
{
    const float* x  = (const float*)d_in[0];
    const float* w7 = (const float*)d_in[1];
    const float* b7 = (const float*)d_in[2];
    const float* w5 = (const float*)d_in[3];
    const float* b5 = (const float*)d_in[4];
    const float* w3 = (const float*)d_in[5];
    const float* b3 = (const float*)d_in[6];
    float* outp = (float*)d_out;

    u16*   weffh = (u16*)d_ws;                               // 512*392*2 = 401,408 B
    float* beff  = (float*)((char*)d_ws + NCH * WH_PER_CH * sizeof(u16)); // +2 KB

    build_weights<<<NCH, 64, 0, stream>>>(w7, b7, w5, b5, w3, b3, weffh, beff);
    dwconv_fused<<<NCH * 8, 256, 0, stream>>>(x, (const u32*)weffh, beff, outp);
}

// Round 3
// 439.567 us; speedup vs baseline: 1.4606x; 1.2496x over previous
//
#include <hip/hip_runtime.h>

typedef _Float16 f16;
typedef _Float16 f16x8 __attribute__((ext_vector_type(8)));
typedef float    f32x4 __attribute__((ext_vector_type(4)));
typedef unsigned int   u32;
typedef unsigned short u16;

#define NCH   512
#define ND    16
#define NH    64
#define NW    64
#define HT    16                 // output rows per block (one 16-row MFMA tile)
#define ROWS  22                 // staged rows = 16 + 3 halo each side
#define RST   88                 // f16 per LDS row (176 B: 16B-aligned, bank stride 12)
#define PLANE 4096
#define CHVOL 65536
#define WH_PER_CH 392            // f16 weights per channel: [kh=7][kd=7][kw pad8]
#define WU_PER_CH 196            // same as dwords
#define WU_PER_KH 28

__device__ __forceinline__ u16 f16bits(float v) {
    return __builtin_bit_cast(u16, (f16)v);
}

// ---------------------------------------------------------------------------
// Prologue: fold w7 + centered(w5) + centered(w3) + identity into one 7^3
// effective kernel per channel, f16, [kh][kd][kw pad8] so each kd-row is
// 4 packed dwords (w0,w1)(w2,w3)(w4,w5)(w6,0). b_eff = b7+b5+b3 (fp32).
// ---------------------------------------------------------------------------
__global__ void build_weights(const float* __restrict__ w7,
                              const float* __restrict__ b7,
                              const float* __restrict__ w5,
                              const float* __restrict__ b5,
                              const float* __restrict__ w3,
                              const float* __restrict__ b3,
                              u16* __restrict__ weffh,
                              float* __restrict__ beff)
{
    const int ch = blockIdx.x;
    for (int i = threadIdx.x; i < WH_PER_CH; i += blockDim.x) {
        const int kh = i / 56;
        const int r  = i - kh * 56;
        const int kd = r >> 3;
        const int kw = r & 7;
        float v = 0.0f;
        if (kw < 7) {
            v = w7[ch * 343 + kd * 49 + kh * 7 + kw];
            if (kd >= 1 && kd <= 5 && kh >= 1 && kh <= 5 && kw >= 1 && kw <= 5)
                v += w5[ch * 125 + (kd - 1) * 25 + (kh - 1) * 5 + (kw - 1)];
            if (kd >= 2 && kd <= 4 && kh >= 2 && kh <= 4 && kw >= 2 && kw <= 4)
                v += w3[ch * 27 + (kd - 2) * 9 + (kh - 2) * 3 + (kw - 2)];
            if (kd == 3 && kh == 3 && kw == 3) v += 1.0f;  // identity/residual
        }
        weffh[ch * WH_PER_CH + kh * 56 + kd * 8 + kw] = f16bits(v);
    }
    if (threadIdx.x == 0) beff[ch] = b7[ch] + b5[ch] + b3[ch];
}

// ---------------------------------------------------------------------------
// Main: block = (ch, 16-row h tile), 4 waves = 4 w-tiles of 16. Wave computes
// a 16x16 (h,w) tile for ALL 16 dout via v_mfma_f32_16x16x32_f16:
//   A[m][k] = in[di][h0+m+kh-3][w0-8+k]  (one ds_read_b128 per lane)
//   B[k][n] = wt_eff[kh][kd][k-n-5]      (Toeplitz band, built from SGPRs)
// accumulating over (kh,kd) into 16 AGPR tiles (dout = di-kd+3).
// ---------------------------------------------------------------------------
__global__ __launch_bounds__(256, 2)
void dwconv_mfma(const float* __restrict__ in,
                 const u32* __restrict__ weffu,
                 const float* __restrict__ beff,
                 float* __restrict__ out)
{
    __shared__ u16 slab[ND * ROWS * RST];   // 61,952 B

    // XCD swizzle: same-channel h-tiles land on one XCD, adjacent in time.
    const int b     = blockIdx.x;
    const int xcd   = b & 7;
    const int local = b >> 3;                 // 0..255
    const int ch    = xcd * 64 + (local >> 2);
    const int ht    = local & 3;
    const int h0    = ht * HT;
    const int tid   = threadIdx.x;

    const float* __restrict__ inb = in + ch * CHVOL;

    // ---- stage: chunks of 4 f16 (aligned float4 global load, b64 LDS write)
    // LDS col = iw + 8 (halo 8 left / pad right); chunk c covers iw = 4c-8.
    // Halo chunks (c<2, c>17) and out-of-range rows are all-zero.
    for (int idx = tid; idx < ND * ROWS * 20; idx += 256) {
        const int di = idx / (ROWS * 20);
        const int rm = idx - di * (ROWS * 20);
        const int r  = rm / 20;
        const int c  = rm - r * 20;
        const int ih = h0 - 3 + r;
        u32 p0 = 0u, p1 = 0u;
        if ((unsigned)ih < (unsigned)NH && c >= 2 && c <= 17) {
            const float4 v = *(const float4*)(inb + di * PLANE + ih * NW + (c * 4 - 8));
            p0 = (u32)f16bits(v.x) | ((u32)f16bits(v.y) << 16);
            p1 = (u32)f16bits(v.z) | ((u32)f16bits(v.w) << 16);
        }
        *(uint2*)(slab + (di * ROWS + r) * RST + c * 4) = make_uint2(p0, p1);
    }
    __syncthreads();

    const int lane = tid & 63;
    const int wv   = tid >> 6;        // wave id -> w-tile
    const int w0   = wv * 16;
    const int n    = lane & 15;       // B/D column (also A row m)
    const int quad = lane >> 4;

    // Per-lane Toeplitz window constants (fixed across all 49 builds):
    // tap index t = k - n - 5, k = quad*8 + j; padded-array f16 offset
    // o = t + 20 -> dword window q0..q0+4 over [10 zeros][W0..W3][10 zeros].
    const int  o    = quad * 8 - n + 15;       // 0..39
    const int  q0   = o >> 1;                  // 0..19
    const bool odd  = (o & 1) != 0;
    int sel[5];
    #pragma unroll
    for (int d = 0; d < 5; ++d) sel[d] = q0 + d - 10;   // W index or out-of-band

    const float bv = beff[ch];
    f32x4 acc[16];
    #pragma unroll
    for (int t = 0; t < 16; ++t) acc[t] = (f32x4){bv, bv, bv, bv};

    const u32* __restrict__ wch = weffu + ch * WU_PER_CH;

    #pragma unroll 1
    for (int kh = 0; kh < 7; ++kh) {
        // 28 block-uniform weight dwords -> SGPRs (s_load)
        u32 W[7][4];
        #pragma unroll
        for (int kd = 0; kd < 7; ++kd)
            #pragma unroll
            for (int d = 0; d < 4; ++d)
                W[kd][d] = wch[kh * WU_PER_KH + kd * 4 + d];

        // build 7 Toeplitz B-fragments (pure VALU; cmp masks hoisted by CSE)
        f16x8 Bf[7];
        #pragma unroll
        for (int kd = 0; kd < 7; ++kd) {
            u32 e[5];
            #pragma unroll
            for (int d = 0; d < 5; ++d) {
                const int s = sel[d];
                u32 t = (s == 0) ? W[kd][0] :
                        (s == 1) ? W[kd][1] :
                        (s == 2) ? W[kd][2] :
                        (s == 3) ? W[kd][3] : 0u;
                e[d] = t;
            }
            uint4 f;
            f.x = odd ? ((e[0] >> 16) | (e[1] << 16)) : e[0];
            f.y = odd ? ((e[1] >> 16) | (e[2] << 16)) : e[1];
            f.z = odd ? ((e[2] >> 16) | (e[3] << 16)) : e[2];
            f.w = odd ? ((e[3] >> 16) | (e[4] << 16)) : e[3];
            Bf[kd] = __builtin_bit_cast(f16x8, f);
        }

        // A-frag per (di): rows m+kh, 16B/lane; fans out to <=7 kd MFMAs
        #pragma unroll
        for (int di = 0; di < ND; ++di) {
            const f16x8 Af = *(const f16x8*)(slab + (di * ROWS + n + kh) * RST
                                             + w0 + quad * 8);
            #pragma unroll
            for (int kd = 0; kd < 7; ++kd) {
                const int dout = di - kd + 3;            // folds at compile time
                if (dout < 0 || dout > 15) continue;
                acc[dout] = __builtin_amdgcn_mfma_f32_16x16x32_f16(
                                Af, Bf[kd], acc[dout], 0, 0, 0);
            }
        }
    }

    // ---- epilogue: D row = quad*4+reg (h), col = n (w); out[..][h*64+w][d]
    float* __restrict__ ob = out + ch * CHVOL;
    #pragma unroll
    for (int r = 0; r < 4; ++r) {
        const int h = h0 + quad * 4 + r;
        float* p = ob + (h * NW + w0 + n) * ND;
        #pragma unroll
        for (int tg = 0; tg < 4; ++tg) {
            const float4 v = make_float4(acc[4 * tg + 0][r], acc[4 * tg + 1][r],
                                         acc[4 * tg + 2][r], acc[4 * tg + 3][r]);
            *(float4*)(p + 4 * tg) = v;
        }
    }
}

extern "C" void kernel_launch(void* const* d_in, const int* in_sizes, int n_in,
                              void* d_out, int out_size, void* d_ws, size_t ws_size,
                              hipStream_t stream)
{
    const float* x  = (const float*)d_in[0];
    const float* w7 = (const float*)d_in[1];
    const float* b7 = (const float*)d_in[2];
    const float* w5 = (const float*)d_in[3];
    const float* b5 = (const float*)d_in[4];
    const float* w3 = (const float*)d_in[5];
    const float* b3 = (const float*)d_in[6];
    float* outp = (float*)d_out;

    u16*   weffh = (u16*)d_ws;                                   // 401,408 B
    float* beff  = (float*)((char*)d_ws + NCH * WH_PER_CH * sizeof(u16));

    build_weights<<<NCH, 64, 0, stream>>>(w7, b7, w5, b5, w3, b3, weffh, beff);
    dwconv_mfma<<<NCH * 4, 256, 0, stream>>>(x, (const u32*)weffh, beff, outp);
}